// Round 16
// baseline (98.765 us; speedup 1.0000x reference)
//
#include <hip/hip_runtime.h>

#define NTEST  16384
#define NTRAIN 8192
#define DIM    64
#define NCOLSPLIT 16
#define WPB    8                            // waves per block (512 threads)

typedef _Float16 f16x8  __attribute__((ext_vector_type(8)));
typedef float    f32x16 __attribute__((ext_vector_type(16)));

#define LOG2E 1.4426950408889634f

// Direct global->LDS DMA: no staging VGPRs, linear wave-contiguous LDS writes.
#define GLOAD_LDS16(gsrc, ldst)                                                     \
    __builtin_amdgcn_global_load_lds(                                               \
        (const __attribute__((address_space(1))) unsigned int*)(gsrc),              \
        (__attribute__((address_space(3))) unsigned int*)(ldst), 16, 0, 0)

// One wave per row. Rows [0,NTEST) = test_X -> A_hi (row-major) + nx2=cn*nx.
// Rows [NTEST,..) = train_X -> B_hi in TILE-MAJOR fragment layout +
// wt = alpha * exp2(cn*nt)  (train-norm folded into the weight).
// hi-only f16 (calibrated: 4x margin, rounds 9-15 measured 1.455e-11).
// Tile-major: for train row r, dim k:
//   flat = (r>>5)*2048 + (k>>4)*512 + (((k>>3)&1)*32 + (r&31))*8 + (k&7)
__global__ __launch_bounds__(256) void krr_prep(
    const float* __restrict__ test_X, const float* __restrict__ train_X,
    const float* __restrict__ alphas, const float* __restrict__ lengthscale,
    _Float16* __restrict__ A_hi, _Float16* __restrict__ B_hi,
    float* __restrict__ nx2, float* __restrict__ wt)
{
    int gwave = (blockIdx.x * 256 + threadIdx.x) >> 6;
    int lane  = threadIdx.x & 63;           // = dim index k
    bool is_test = gwave < NTEST;
    int row = is_test ? gwave : gwave - NTEST;
    const float* src = is_test ? test_X : train_X;

    float x = src[(size_t)row * DIM + lane];
    _Float16 h = (_Float16)x;                // RNE to f16

    if (is_test) {
        A_hi[(size_t)row * DIM + lane] = h;
    } else {
        int t  = row >> 5, lr = row & 31;
        int kk = lane >> 4, hi = (lane >> 3) & 1, e = lane & 7;
        size_t dst = (size_t)t * 2048 + (size_t)kk * 512 + (size_t)(hi * 32 + lr) * 8 + e;
        B_hi[dst] = h;
    }

    float s = x * x;
    s += __shfl_xor(s, 1);  s += __shfl_xor(s, 2);  s += __shfl_xor(s, 4);
    s += __shfl_xor(s, 8);  s += __shfl_xor(s, 16); s += __shfl_xor(s, 32);
    if (lane == 0) {
        float ls   = lengthscale[0];
        float inv2 = 1.0f / (ls * ls);
        float cn   = -0.5f * inv2 * LOG2E;   // log2-domain norm coefficient
        if (is_test) nx2[row] = s * cn;
        else         wt[row]  = alphas[row] * __builtin_amdgcn_exp2f(cn * s);
    }
}

// PIPELINED LDS staging (T3-minimum): 4 units x 4 tiles (16KB), two NAMED
// buffers BsA/BsB, straight-line phase schedule (no runtime buffer index —
// rule #20). Each stage-issue precedes a 4-tile compute segment; the
// following barrier's vmcnt-drain is then covered (~1300 cyc of compute vs
// ~600 cyc load latency). Only unit 0's wait is exposed, once per WG.
// 34KB LDS -> 4 WG/CU; VGPR ~60 -> full 32-wave/CU occupancy reachable.
// Per-wave math identical to r13/r15 (2-tile ILP pairs).
// K*alpha = exp2(s1*C + nx2[row]) * wt[col].
__global__ __launch_bounds__(512) void krr_mfma(
    const _Float16* __restrict__ A_hi, const _Float16* __restrict__ B_hi,
    const float* __restrict__ nx2, const float* __restrict__ wt,
    const float* __restrict__ lengthscale, float* __restrict__ out)
{
    alignas(16) __shared__ _Float16 BsA[4 * 2048];  // 16 KB
    alignas(16) __shared__ _Float16 BsB[4 * 2048];  // 16 KB
    __shared__ float wts[512];                      // 2 KB

    const int tid   = threadIdx.x;
    const int lane  = tid & 63;
    const int wave  = tid >> 6;
    const int rbase = blockIdx.x * 256 + wave * 32;
    const int cb    = blockIdx.y;                   // col-split index

    const float ls   = lengthscale[0];
    const float inv2 = 1.0f / (ls * ls);
    const float s1   = inv2 * LOG2E;         // dot coefficient (log2 domain)

    // Stage the strip's weights once (512 threads x 4B, conflict-free).
    wts[tid] = wt[cb * 512 + tid];

    const int arow = rbase + (lane & 31);
    const int koff = (lane >> 5) * 8;        // canonical k-map, same for A and B

    // A fragments, loop-invariant: 4 x 16B = 16 VGPRs
    f16x8 ah[4];
    #pragma unroll
    for (int kk = 0; kk < 4; ++kk)
        ah[kk] = *reinterpret_cast<const f16x8*>(A_hi + (size_t)arow * DIM + kk * 16 + koff);

    // per-lane row constants: cn*nx for the 16 C/D rows this lane holds
    float nxc[16];
    #pragma unroll
    for (int r = 0; r < 16; ++r) {
        int row = (r & 3) + 8 * (r >> 2) + 4 * (lane >> 5);
        nxc[r] = nx2[rbase + row];
    }

    float acc[16];
    #pragma unroll
    for (int r = 0; r < 16; ++r) acc[r] = 0.0f;

    // Stage unit u (4 tiles = 16KB): wave w covers 2KB via 2 x 1KB DMA.
    #define STAGE_UNIT(u, buf)                                                  \
        {                                                                       \
            const _Float16* g = B_hi + ((size_t)cb * 16 + (u) * 4) * 2048       \
                              + (size_t)wave * 1024 + (size_t)lane * 8;         \
            _Float16* l = (buf) + (size_t)wave * 1024;                          \
            GLOAD_LDS16(g,       l);                                            \
            GLOAD_LDS16(g + 512, l + 512);                                      \
        }

    // Compute 4 tiles of `buf` (unit u), two at a time (independent chains).
    auto compute4 = [&](const _Float16* buf, int u) {
        #pragma unroll
        for (int lt = 0; lt < 4; lt += 2) {
            const _Float16* pA = buf + (size_t)lt * 2048 + (size_t)lane * 8;
            const _Float16* pB = pA + 2048;
            f16x8 bhA[4], bhB[4];
            #pragma unroll
            for (int kk = 0; kk < 4; ++kk) {
                bhA[kk] = *reinterpret_cast<const f16x8*>(pA + kk * 512);
                bhB[kk] = *reinterpret_cast<const f16x8*>(pB + kk * 512);
            }
            const int wtb = u * 128 + lt * 32 + (lane & 31);
            const float wA = wts[wtb];
            const float wB = wts[wtb + 32];

            f32x16 CA = {};
            f32x16 CB = {};
            #pragma unroll
            for (int kk = 0; kk < 4; ++kk) {
                CA = __builtin_amdgcn_mfma_f32_32x32x16_f16(ah[kk], bhA[kk], CA, 0, 0, 0);
                CB = __builtin_amdgcn_mfma_f32_32x32x16_f16(ah[kk], bhB[kk], CB, 0, 0, 0);
            }

            #pragma unroll
            for (int r = 0; r < 16; ++r) {
                float argA = fmaf(CA[r], s1, nxc[r]);    // log2 domain
                float argB = fmaf(CB[r], s1, nxc[r]);
                acc[r] = fmaf(__builtin_amdgcn_exp2f(argA), wA, acc[r]);
                acc[r] = fmaf(__builtin_amdgcn_exp2f(argB), wB, acc[r]);
            }
        }
    };

    // Straight-line pipeline: stage-issue before compute; each barrier's
    // vmcnt(0)-drain is covered by the preceding compute segment.
    STAGE_UNIT(0, BsA);
    __syncthreads();                  // exposed wait: unit 0 only
    STAGE_UNIT(1, BsB);
    compute4(BsA, 0);
    __syncthreads();                  // drains U1 (hidden under compute)
    STAGE_UNIT(2, BsA);
    compute4(BsB, 1);
    __syncthreads();                  // drains U2 (hidden)
    STAGE_UNIT(3, BsB);
    compute4(BsA, 2);
    __syncthreads();                  // drains U3 (hidden)
    compute4(BsB, 3);

    #undef STAGE_UNIT

    // Sum over the 32 train cols held across lanes of the same half.
    #pragma unroll
    for (int r = 0; r < 16; ++r) {
        float v = acc[r];
        v += __shfl_xor(v, 1);  v += __shfl_xor(v, 2);  v += __shfl_xor(v, 4);
        v += __shfl_xor(v, 8);  v += __shfl_xor(v, 16);
        if ((lane & 31) == 0) {
            int row = (r & 3) + 8 * (r >> 2) + 4 * (lane >> 5);
            atomicAdd(&out[rbase + row], v);
        }
    }
}

// ---------------- fallback (round-1 kernel, known-good) ----------------
#define TCHUNK 512
#define NCHUNK (NTRAIN / TCHUNK)
__global__ __launch_bounds__(256, 4) void krr_main(
    const float* __restrict__ test_X, const float* __restrict__ train_X,
    const float* __restrict__ alphas, const float* __restrict__ lengthscale,
    float* __restrict__ out)
{
    __shared__ float nt_lds[TCHUNK];
    __shared__ float al_lds[TCHUNK];
    const int tid = threadIdx.x;
    const int i   = blockIdx.x * 256 + tid;
    const int j0  = blockIdx.y * TCHUNK;
    const float ls   = lengthscale[0];
    const float inv2 = 1.0f / (ls * ls);
    for (int jj = tid; jj < TCHUNK; jj += 256) {
        const float4* tr = reinterpret_cast<const float4*>(train_X + (size_t)(j0 + jj) * DIM);
        float s = 0.f;
        #pragma unroll
        for (int k = 0; k < DIM / 4; ++k) {
            float4 t = tr[k];
            s += t.x * t.x + t.y * t.y + t.z * t.z + t.w * t.w;
        }
        nt_lds[jj] = s * inv2;
        al_lds[jj] = alphas[j0 + jj];
    }
    __syncthreads();
    float xr[DIM]; float nxv = 0.f;
    {
        const float4* xp = reinterpret_cast<const float4*>(test_X + (size_t)i * DIM);
        #pragma unroll
        for (int k = 0; k < DIM / 4; ++k) {
            float4 v = xp[k];
            xr[4*k+0] = v.x; xr[4*k+1] = v.y; xr[4*k+2] = v.z; xr[4*k+3] = v.w;
            nxv += v.x*v.x + v.y*v.y + v.z*v.z + v.w*v.w;
        }
        nxv *= inv2;
        #pragma unroll
        for (int k = 0; k < DIM; ++k) xr[k] *= inv2;
    }
    float acc = 0.f;
    for (int jj = 0; jj < TCHUNK; ++jj) {
        const float* trow = train_X + (size_t)(j0 + jj) * DIM;
        float d0 = 0.f, d1 = 0.f, d2 = 0.f, d3 = 0.f;
        #pragma unroll
        for (int k4 = 0; k4 < DIM / 4; ++k4) {
            float4 t = reinterpret_cast<const float4*>(trow)[k4];
            d0 = fmaf(xr[4*k4+0], t.x, d0);
            d1 = fmaf(xr[4*k4+1], t.y, d1);
            d2 = fmaf(xr[4*k4+2], t.z, d2);
            d3 = fmaf(xr[4*k4+3], t.w, d3);
        }
        float dot = (d0 + d1) + (d2 + d3);
        float sq  = nxv + nt_lds[jj] - 2.0f * dot;
        sq = fmaxf(sq, 0.0f);
        acc = fmaf(__expf(-0.5f * sq), al_lds[jj], acc);
    }
    atomicAdd(&out[i], acc);
}

extern "C" void kernel_launch(void* const* d_in, const int* in_sizes, int n_in,
                              void* d_out, int out_size, void* d_ws, size_t ws_size,
                              hipStream_t stream) {
    const float* test_X      = (const float*)d_in[0];
    const float* train_X     = (const float*)d_in[1];
    const float* alphas      = (const float*)d_in[2];
    const float* lengthscale = (const float*)d_in[3];
    float* out = (float*)d_out;

    hipMemsetAsync(out, 0, NTEST * sizeof(float), stream);

    const size_t need = (size_t)(NTEST + NTRAIN) * DIM * sizeof(_Float16)
                      + (NTEST + NTRAIN) * sizeof(float);
    if (ws_size >= need) {
        _Float16* A_hi = (_Float16*)d_ws;
        _Float16* B_hi = A_hi + (size_t)NTEST * DIM;
        float*    nx2  = (float*)(B_hi + (size_t)NTRAIN * DIM);
        float*    wtp  = nx2 + NTEST;

        krr_prep<<<(NTEST + NTRAIN) / 4, 256, 0, stream>>>(
            test_X, train_X, alphas, lengthscale, A_hi, B_hi, nx2, wtp);

        dim3 grid(NTEST / 256, NCOLSPLIT);
        krr_mfma<<<grid, 64 * WPB, 0, stream>>>(A_hi, B_hi, nx2, wtp,
                                                lengthscale, out);
    } else {
        dim3 grid(NTEST / 256, NCHUNK);
        krr_main<<<grid, 256, 0, stream>>>(test_X, train_X, alphas, lengthscale, out);
    }
}

// Round 17
// 44.954 us; speedup vs baseline: 2.1970x; 2.1970x over previous
//
#include <hip/hip_runtime.h>

#define NTEST  16384
#define NTRAIN 8192
#define DIM    64
#define NCOLSPLIT 16
#define WPB    8                            // waves per block (512 threads)

typedef _Float16 f16x8  __attribute__((ext_vector_type(8)));
typedef float    f32x16 __attribute__((ext_vector_type(16)));

#define LOG2E 1.4426950408889634f

// Direct global->LDS DMA: no staging VGPRs, linear wave-contiguous LDS writes.
#define GLOAD_LDS16(gsrc, ldst)                                                     \
    __builtin_amdgcn_global_load_lds(                                               \
        (const __attribute__((address_space(1))) unsigned int*)(gsrc),              \
        (__attribute__((address_space(3))) unsigned int*)(ldst), 16, 0, 0)

// One wave per row. Rows [0,NTEST) = test_X -> A_hi (row-major) + nx2=cn*nx.
// Rows [NTEST,..) = train_X -> B_hi in TILE-MAJOR fragment layout +
// wt = alpha * exp2(cn*nt)  (train-norm folded into the weight).
// hi-only f16 (calibrated: 4x margin, rounds 9-16 measured 1.455e-11).
// Tile-major: for train row r, dim k:
//   flat = (r>>5)*2048 + (k>>4)*512 + (((k>>3)&1)*32 + (r&31))*8 + (k&7)
__global__ __launch_bounds__(256) void krr_prep(
    const float* __restrict__ test_X, const float* __restrict__ train_X,
    const float* __restrict__ alphas, const float* __restrict__ lengthscale,
    _Float16* __restrict__ A_hi, _Float16* __restrict__ B_hi,
    float* __restrict__ nx2, float* __restrict__ wt)
{
    int gwave = (blockIdx.x * 256 + threadIdx.x) >> 6;
    int lane  = threadIdx.x & 63;           // = dim index k
    bool is_test = gwave < NTEST;
    int row = is_test ? gwave : gwave - NTEST;
    const float* src = is_test ? test_X : train_X;

    float x = src[(size_t)row * DIM + lane];
    _Float16 h = (_Float16)x;                // RNE to f16

    if (is_test) {
        A_hi[(size_t)row * DIM + lane] = h;
    } else {
        int t  = row >> 5, lr = row & 31;
        int kk = lane >> 4, hi = (lane >> 3) & 1, e = lane & 7;
        size_t dst = (size_t)t * 2048 + (size_t)kk * 512 + (size_t)(hi * 32 + lr) * 8 + e;
        B_hi[dst] = h;
    }

    float s = x * x;
    s += __shfl_xor(s, 1);  s += __shfl_xor(s, 2);  s += __shfl_xor(s, 4);
    s += __shfl_xor(s, 8);  s += __shfl_xor(s, 16); s += __shfl_xor(s, 32);
    if (lane == 0) {
        float ls   = lengthscale[0];
        float inv2 = 1.0f / (ls * ls);
        float cn   = -0.5f * inv2 * LOG2E;   // log2-domain norm coefficient
        if (is_test) nx2[row] = s * cn;
        else         wt[row]  = alphas[row] * __builtin_amdgcn_exp2f(cn * s);
    }
}

// r15 STRUCTURE (proven clean: 45.5us, no spill) + ONE change: phase-1's
// stage is ISSUED before phase-0's compute, so its ~600cyc latency hides
// under ~1000cyc of MFMA/epilogue; the following barrier's vmcnt-drain is
// then nearly free. 2 barriers total (was 3), double-buffered BsA/BsB
// (named — rule #20), 66KB LDS -> 2 WG/CU.
// SPILL RULE (r14/r16 lessons): the body tolerates exactly ONE 2-tile
// compute live set; both compute loops stay '#pragma unroll 1' so the
// scheduler cannot fuse segments. Staging adds only address registers
// (global_load_lds has no data regs). Math identical to r13/r15.
// K*alpha = exp2(s1*C + nx2[row]) * wt[col].
__global__ __launch_bounds__(512) void krr_mfma(
    const _Float16* __restrict__ A_hi, const _Float16* __restrict__ B_hi,
    const float* __restrict__ nx2, const float* __restrict__ wt,
    const float* __restrict__ lengthscale, float* __restrict__ out)
{
    alignas(16) __shared__ _Float16 BsA[8 * 2048];  // 32 KB (phase 0)
    alignas(16) __shared__ _Float16 BsB[8 * 2048];  // 32 KB (phase 1)
    __shared__ float wts[512];                      // 2 KB

    const int tid   = threadIdx.x;
    const int lane  = tid & 63;
    const int wave  = tid >> 6;
    const int rbase = blockIdx.x * 256 + wave * 32;
    const int cb    = blockIdx.y;                   // col-split index

    const float ls   = lengthscale[0];
    const float inv2 = 1.0f / (ls * ls);
    const float s1   = inv2 * LOG2E;         // dot coefficient (log2 domain)

    // Wave w DMAs tile (p*8 + w) of the strip: 4 x 1KB global_load_lds.
    #define STAGE8(p, buf)                                                      \
        {                                                                       \
            const _Float16* gt = B_hi + ((size_t)cb * 16 + (p) * 8 + wave) * 2048 \
                               + (size_t)lane * 8;                              \
            _Float16* lt0 = (buf) + (size_t)wave * 2048;                        \
            GLOAD_LDS16(gt,        lt0);                                        \
            GLOAD_LDS16(gt + 512,  lt0 + 512);                                  \
            GLOAD_LDS16(gt + 1024, lt0 + 1024);                                 \
            GLOAD_LDS16(gt + 1536, lt0 + 1536);                                 \
        }

    // Compute 8 tiles of phase p from buf, two at a time. MUST stay a
    // '#pragma unroll 1' loop (live-range barrier — see header comment).
    #define COMPUTE8(p, buf)                                                    \
        _Pragma("unroll 1")                                                     \
        for (int lt = 0; lt < 8; lt += 2) {                                     \
            const _Float16* pA = (buf) + (size_t)lt * 2048 + (size_t)lane * 8;  \
            const _Float16* pB = pA + 2048;                                     \
            f16x8 bhA[4], bhB[4];                                               \
            _Pragma("unroll")                                                   \
            for (int kk = 0; kk < 4; ++kk) {                                    \
                bhA[kk] = *reinterpret_cast<const f16x8*>(pA + kk * 512);       \
                bhB[kk] = *reinterpret_cast<const f16x8*>(pB + kk * 512);       \
            }                                                                   \
            const int wtb = ((p) * 8 + lt) * 32 + (lane & 31);                  \
            const float wA = wts[wtb];                                          \
            const float wB = wts[wtb + 32];                                     \
            f32x16 CA = {};                                                     \
            f32x16 CB = {};                                                     \
            _Pragma("unroll")                                                   \
            for (int kk = 0; kk < 4; ++kk) {                                    \
                CA = __builtin_amdgcn_mfma_f32_32x32x16_f16(ah[kk], bhA[kk], CA, 0, 0, 0); \
                CB = __builtin_amdgcn_mfma_f32_32x32x16_f16(ah[kk], bhB[kk], CB, 0, 0, 0); \
            }                                                                   \
            _Pragma("unroll")                                                   \
            for (int r = 0; r < 16; ++r) {                                      \
                float argA = fmaf(CA[r], s1, nxc[r]);                           \
                float argB = fmaf(CB[r], s1, nxc[r]);                           \
                acc[r] = fmaf(__builtin_amdgcn_exp2f(argA), wA, acc[r]);        \
                acc[r] = fmaf(__builtin_amdgcn_exp2f(argB), wB, acc[r]);        \
            }                                                                   \
        }

    // Issue phase-0 stage + weights immediately.
    STAGE8(0, BsA);
    wts[tid] = wt[cb * 512 + tid];

    const int arow = rbase + (lane & 31);
    const int koff = (lane >> 5) * 8;        // canonical k-map, same for A and B

    // A fragments, loop-invariant: 4 x 16B = 16 VGPRs
    f16x8 ah[4];
    #pragma unroll
    for (int kk = 0; kk < 4; ++kk)
        ah[kk] = *reinterpret_cast<const f16x8*>(A_hi + (size_t)arow * DIM + kk * 16 + koff);

    // per-lane row constants: cn*nx for the 16 C/D rows this lane holds
    float nxc[16];
    #pragma unroll
    for (int r = 0; r < 16; ++r) {
        int row = (r & 3) + 8 * (r >> 2) + 4 * (lane >> 5);
        nxc[r] = nx2[rbase + row];
    }

    float acc[16];
    #pragma unroll
    for (int r = 0; r < 16; ++r) acc[r] = 0.0f;

    __syncthreads();              // BsA ready (the one exposed stage wait)

    STAGE8(1, BsB);               // issued now; latency hidden under COMPUTE8(0)
    COMPUTE8(0, BsA);

    __syncthreads();              // drains BsB loads (covered by compute above)

    COMPUTE8(1, BsB);

    #undef STAGE8
    #undef COMPUTE8

    // Sum over the 32 train cols held across lanes of the same half.
    #pragma unroll
    for (int r = 0; r < 16; ++r) {
        float v = acc[r];
        v += __shfl_xor(v, 1);  v += __shfl_xor(v, 2);  v += __shfl_xor(v, 4);
        v += __shfl_xor(v, 8);  v += __shfl_xor(v, 16);
        if ((lane & 31) == 0) {
            int row = (r & 3) + 8 * (r >> 2) + 4 * (lane >> 5);
            atomicAdd(&out[rbase + row], v);
        }
    }
}

// ---------------- fallback (round-1 kernel, known-good) ----------------
#define TCHUNK 512
#define NCHUNK (NTRAIN / TCHUNK)
__global__ __launch_bounds__(256, 4) void krr_main(
    const float* __restrict__ test_X, const float* __restrict__ train_X,
    const float* __restrict__ alphas, const float* __restrict__ lengthscale,
    float* __restrict__ out)
{
    __shared__ float nt_lds[TCHUNK];
    __shared__ float al_lds[TCHUNK];
    const int tid = threadIdx.x;
    const int i   = blockIdx.x * 256 + tid;
    const int j0  = blockIdx.y * TCHUNK;
    const float ls   = lengthscale[0];
    const float inv2 = 1.0f / (ls * ls);
    for (int jj = tid; jj < TCHUNK; jj += 256) {
        const float4* tr = reinterpret_cast<const float4*>(train_X + (size_t)(j0 + jj) * DIM);
        float s = 0.f;
        #pragma unroll
        for (int k = 0; k < DIM / 4; ++k) {
            float4 t = tr[k];
            s += t.x * t.x + t.y * t.y + t.z * t.z + t.w * t.w;
        }
        nt_lds[jj] = s * inv2;
        al_lds[jj] = alphas[j0 + jj];
    }
    __syncthreads();
    float xr[DIM]; float nxv = 0.f;
    {
        const float4* xp = reinterpret_cast<const float4*>(test_X + (size_t)i * DIM);
        #pragma unroll
        for (int k = 0; k < DIM / 4; ++k) {
            float4 v = xp[k];
            xr[4*k+0] = v.x; xr[4*k+1] = v.y; xr[4*k+2] = v.z; xr[4*k+3] = v.w;
            nxv += v.x*v.x + v.y*v.y + v.z*v.z + v.w*v.w;
        }
        nxv *= inv2;
        #pragma unroll
        for (int k = 0; k < DIM; ++k) xr[k] *= inv2;
    }
    float acc = 0.f;
    for (int jj = 0; jj < TCHUNK; ++jj) {
        const float* trow = train_X + (size_t)(j0 + jj) * DIM;
        float d0 = 0.f, d1 = 0.f, d2 = 0.f, d3 = 0.f;
        #pragma unroll
        for (int k4 = 0; k4 < DIM / 4; ++k4) {
            float4 t = reinterpret_cast<const float4*>(trow)[k4];
            d0 = fmaf(xr[4*k4+0], t.x, d0);
            d1 = fmaf(xr[4*k4+1], t.y, d1);
            d2 = fmaf(xr[4*k4+2], t.z, d2);
            d3 = fmaf(xr[4*k4+3], t.w, d3);
        }
        float dot = (d0 + d1) + (d2 + d3);
        float sq  = nxv + nt_lds[jj] - 2.0f * dot;
        sq = fmaxf(sq, 0.0f);
        acc = fmaf(__expf(-0.5f * sq), al_lds[jj], acc);
    }
    atomicAdd(&out[i], acc);
}

extern "C" void kernel_launch(void* const* d_in, const int* in_sizes, int n_in,
                              void* d_out, int out_size, void* d_ws, size_t ws_size,
                              hipStream_t stream) {
    const float* test_X      = (const float*)d_in[0];
    const float* train_X     = (const float*)d_in[1];
    const float* alphas      = (const float*)d_in[2];
    const float* lengthscale = (const float*)d_in[3];
    float* out = (float*)d_out;

    hipMemsetAsync(out, 0, NTEST * sizeof(float), stream);

    const size_t need = (size_t)(NTEST + NTRAIN) * DIM * sizeof(_Float16)
                      + (NTEST + NTRAIN) * sizeof(float);
    if (ws_size >= need) {
        _Float16* A_hi = (_Float16*)d_ws;
        _Float16* B_hi = A_hi + (size_t)NTEST * DIM;
        float*    nx2  = (float*)(B_hi + (size_t)NTRAIN * DIM);
        float*    wtp  = nx2 + NTEST;

        krr_prep<<<(NTEST + NTRAIN) / 4, 256, 0, stream>>>(
            test_X, train_X, alphas, lengthscale, A_hi, B_hi, nx2, wtp);

        dim3 grid(NTEST / 256, NCOLSPLIT);
        krr_mfma<<<grid, 64 * WPB, 0, stream>>>(A_hi, B_hi, nx2, wtp,
                                                lengthscale, out);
    } else {
        dim3 grid(NTEST / 256, NCHUNK);
        krr_main<<<grid, 256, 0, stream>>>(test_X, train_X, alphas, lengthscale, out);
    }
}

// Round 18
// 42.218 us; speedup vs baseline: 2.3394x; 1.0648x over previous
//
#include <hip/hip_runtime.h>

#define NTEST  16384
#define NTRAIN 8192
#define DIM    64
#define NCOLSPLIT 16
#define WPB    8                            // waves per block (512 threads)

typedef _Float16 f16x8  __attribute__((ext_vector_type(8)));
typedef float    f32x16 __attribute__((ext_vector_type(16)));

#define LOG2E 1.4426950408889634f

// Direct global->LDS DMA: no staging VGPRs, linear wave-contiguous LDS writes.
#define GLOAD_LDS16(gsrc, ldst)                                                     \
    __builtin_amdgcn_global_load_lds(                                               \
        (const __attribute__((address_space(1))) unsigned int*)(gsrc),              \
        (__attribute__((address_space(3))) unsigned int*)(ldst), 16, 0, 0)

// One wave per row. Rows [0,NTEST) = test_X -> A_hi (row-major) + nx2=cn*nx
// (+ zeroes out[row] — memset launch folded in). Rows [NTEST,..) = train_X ->
// B_hi in TILE-MAJOR fragment layout + wt = alpha * exp2(cn*nt).
// hi-only f16 (calibrated: 4x margin, rounds 9-17 measured 1.455e-11).
// Tile-major: for train row r, dim k:
//   flat = (r>>5)*2048 + (k>>4)*512 + (((k>>3)&1)*32 + (r&31))*8 + (k&7)
__global__ __launch_bounds__(256) void krr_prep(
    const float* __restrict__ test_X, const float* __restrict__ train_X,
    const float* __restrict__ alphas, const float* __restrict__ lengthscale,
    _Float16* __restrict__ A_hi, _Float16* __restrict__ B_hi,
    float* __restrict__ nx2, float* __restrict__ wt, float* __restrict__ out)
{
    int gwave = (blockIdx.x * 256 + threadIdx.x) >> 6;
    int lane  = threadIdx.x & 63;           // = dim index k
    bool is_test = gwave < NTEST;
    int row = is_test ? gwave : gwave - NTEST;
    const float* src = is_test ? test_X : train_X;

    float x = src[(size_t)row * DIM + lane];
    _Float16 h = (_Float16)x;                // RNE to f16

    if (is_test) {
        A_hi[(size_t)row * DIM + lane] = h;
    } else {
        int t  = row >> 5, lr = row & 31;
        int kk = lane >> 4, hi = (lane >> 3) & 1, e = lane & 7;
        size_t dst = (size_t)t * 2048 + (size_t)kk * 512 + (size_t)(hi * 32 + lr) * 8 + e;
        B_hi[dst] = h;
    }

    float s = x * x;
    s += __shfl_xor(s, 1);  s += __shfl_xor(s, 2);  s += __shfl_xor(s, 4);
    s += __shfl_xor(s, 8);  s += __shfl_xor(s, 16); s += __shfl_xor(s, 32);
    if (lane == 0) {
        float ls   = lengthscale[0];
        float inv2 = 1.0f / (ls * ls);
        float cn   = -0.5f * inv2 * LOG2E;   // log2-domain norm coefficient
        if (is_test) { nx2[row] = s * cn; out[row] = 0.0f; }
        else         wt[row]  = alphas[row] * __builtin_amdgcn_exp2f(cn * s);
    }
}

// r17 structure + TILE-LEVEL TIME-SHARE ROTATION (HK T16 idea): within each
// phase, the NEXT pair's ds_reads are issued into the SAME bhA/bhB registers
// right after the MFMAs consume them (MFMA reads operands at issue; the
// compiler enforces the WAR), BEFORE the 48-inst epilogue — so LDS latency
// hides under epilogue VALU/trans instead of stalling the next MFMA chain.
// No extra buffers: VGPR ~124, below the observed ~128 spill heuristic
// (r14/r16 lessons). Outer loops stay '#pragma unroll 1' (live-range
// barrier). Math identical to r13-r17. K*alpha = exp2(s1*C+nx2[row])*wt[col].
__global__ __launch_bounds__(512) void krr_mfma(
    const _Float16* __restrict__ A_hi, const _Float16* __restrict__ B_hi,
    const float* __restrict__ nx2, const float* __restrict__ wt,
    const float* __restrict__ lengthscale, float* __restrict__ out)
{
    alignas(16) __shared__ _Float16 BsA[8 * 2048];  // 32 KB (phase 0)
    alignas(16) __shared__ _Float16 BsB[8 * 2048];  // 32 KB (phase 1)
    __shared__ float wts[512];                      // 2 KB

    const int tid   = threadIdx.x;
    const int lane  = tid & 63;
    const int wave  = tid >> 6;
    const int rbase = blockIdx.x * 256 + wave * 32;
    const int cb    = blockIdx.y;                   // col-split index

    const float ls   = lengthscale[0];
    const float inv2 = 1.0f / (ls * ls);
    const float s1   = inv2 * LOG2E;         // dot coefficient (log2 domain)

    // Wave w DMAs tile (p*8 + w) of the strip: 4 x 1KB global_load_lds.
    #define STAGE8(p, buf)                                                      \
        {                                                                       \
            const _Float16* gt = B_hi + ((size_t)cb * 16 + (p) * 8 + wave) * 2048 \
                               + (size_t)lane * 8;                              \
            _Float16* lt0 = (buf) + (size_t)wave * 2048;                        \
            GLOAD_LDS16(gt,        lt0);                                        \
            GLOAD_LDS16(gt + 512,  lt0 + 512);                                  \
            GLOAD_LDS16(gt + 1024, lt0 + 1024);                                 \
            GLOAD_LDS16(gt + 1536, lt0 + 1536);                                 \
        }

    // Compute 8 tiles of phase p: pair-rotated. Preheader loads pair 0;
    // inside the loop the next pair's loads are issued between the MFMA
    // chains and the epilogue (latency hidden under epilogue VALU/trans).
    #define COMPUTE8(p, buf)                                                    \
        {                                                                       \
            const _Float16* pbase = (buf) + (size_t)lane * 8;                   \
            f16x8 bhA[4], bhB[4];                                               \
            _Pragma("unroll")                                                   \
            for (int kk = 0; kk < 4; ++kk) {                                    \
                bhA[kk] = *reinterpret_cast<const f16x8*>(pbase + kk * 512);    \
                bhB[kk] = *reinterpret_cast<const f16x8*>(pbase + 2048 + kk * 512); \
            }                                                                   \
            _Pragma("unroll 1")                                                 \
            for (int lt = 0; lt < 8; lt += 2) {                                 \
                f32x16 CA = {};                                                 \
                f32x16 CB = {};                                                 \
                _Pragma("unroll")                                               \
                for (int kk = 0; kk < 4; ++kk) {                                \
                    CA = __builtin_amdgcn_mfma_f32_32x32x16_f16(ah[kk], bhA[kk], CA, 0, 0, 0); \
                    CB = __builtin_amdgcn_mfma_f32_32x32x16_f16(ah[kk], bhB[kk], CB, 0, 0, 0); \
                }                                                               \
                const int wtb = ((p) * 8 + lt) * 32 + (lane & 31);              \
                const float wA = wts[wtb];                                      \
                const float wB = wts[wtb + 32];                                 \
                if (lt < 6) {                                                   \
                    const _Float16* pn = pbase + (size_t)(lt + 2) * 2048;       \
                    _Pragma("unroll")                                           \
                    for (int kk = 0; kk < 4; ++kk) {                            \
                        bhA[kk] = *reinterpret_cast<const f16x8*>(pn + kk * 512); \
                        bhB[kk] = *reinterpret_cast<const f16x8*>(pn + 2048 + kk * 512); \
                    }                                                           \
                }                                                               \
                _Pragma("unroll")                                               \
                for (int r = 0; r < 16; ++r) {                                  \
                    float argA = fmaf(CA[r], s1, nxc[r]);                       \
                    float argB = fmaf(CB[r], s1, nxc[r]);                       \
                    acc[r] = fmaf(__builtin_amdgcn_exp2f(argA), wA, acc[r]);    \
                    acc[r] = fmaf(__builtin_amdgcn_exp2f(argB), wB, acc[r]);    \
                }                                                               \
            }                                                                   \
        }

    // Issue phase-0 stage + weights immediately.
    STAGE8(0, BsA);
    wts[tid] = wt[cb * 512 + tid];

    const int arow = rbase + (lane & 31);
    const int koff = (lane >> 5) * 8;        // canonical k-map, same for A and B

    // A fragments, loop-invariant: 4 x 16B = 16 VGPRs
    f16x8 ah[4];
    #pragma unroll
    for (int kk = 0; kk < 4; ++kk)
        ah[kk] = *reinterpret_cast<const f16x8*>(A_hi + (size_t)arow * DIM + kk * 16 + koff);

    // per-lane row constants: cn*nx for the 16 C/D rows this lane holds
    float nxc[16];
    #pragma unroll
    for (int r = 0; r < 16; ++r) {
        int row = (r & 3) + 8 * (r >> 2) + 4 * (lane >> 5);
        nxc[r] = nx2[rbase + row];
    }

    float acc[16];
    #pragma unroll
    for (int r = 0; r < 16; ++r) acc[r] = 0.0f;

    __syncthreads();              // BsA ready (the one exposed stage wait)

    STAGE8(1, BsB);               // issued now; latency hidden under COMPUTE8(0)
    COMPUTE8(0, BsA);

    __syncthreads();              // drains BsB loads (covered by compute above)

    COMPUTE8(1, BsB);

    #undef STAGE8
    #undef COMPUTE8

    // Sum over the 32 train cols held across lanes of the same half.
    #pragma unroll
    for (int r = 0; r < 16; ++r) {
        float v = acc[r];
        v += __shfl_xor(v, 1);  v += __shfl_xor(v, 2);  v += __shfl_xor(v, 4);
        v += __shfl_xor(v, 8);  v += __shfl_xor(v, 16);
        if ((lane & 31) == 0) {
            int row = (r & 3) + 8 * (r >> 2) + 4 * (lane >> 5);
            atomicAdd(&out[rbase + row], v);
        }
    }
}

// ---------------- fallback (round-1 kernel, known-good) ----------------
#define TCHUNK 512
#define NCHUNK (NTRAIN / TCHUNK)
__global__ __launch_bounds__(256, 4) void krr_main(
    const float* __restrict__ test_X, const float* __restrict__ train_X,
    const float* __restrict__ alphas, const float* __restrict__ lengthscale,
    float* __restrict__ out)
{
    __shared__ float nt_lds[TCHUNK];
    __shared__ float al_lds[TCHUNK];
    const int tid = threadIdx.x;
    const int i   = blockIdx.x * 256 + tid;
    const int j0  = blockIdx.y * TCHUNK;
    const float ls   = lengthscale[0];
    const float inv2 = 1.0f / (ls * ls);
    for (int jj = tid; jj < TCHUNK; jj += 256) {
        const float4* tr = reinterpret_cast<const float4*>(train_X + (size_t)(j0 + jj) * DIM);
        float s = 0.f;
        #pragma unroll
        for (int k = 0; k < DIM / 4; ++k) {
            float4 t = tr[k];
            s += t.x * t.x + t.y * t.y + t.z * t.z + t.w * t.w;
        }
        nt_lds[jj] = s * inv2;
        al_lds[jj] = alphas[j0 + jj];
    }
    __syncthreads();
    float xr[DIM]; float nxv = 0.f;
    {
        const float4* xp = reinterpret_cast<const float4*>(test_X + (size_t)i * DIM);
        #pragma unroll
        for (int k = 0; k < DIM / 4; ++k) {
            float4 v = xp[k];
            xr[4*k+0] = v.x; xr[4*k+1] = v.y; xr[4*k+2] = v.z; xr[4*k+3] = v.w;
            nxv += v.x*v.x + v.y*v.y + v.z*v.z + v.w*v.w;
        }
        nxv *= inv2;
        #pragma unroll
        for (int k = 0; k < DIM; ++k) xr[k] *= inv2;
    }
    float acc = 0.f;
    for (int jj = 0; jj < TCHUNK; ++jj) {
        const float* trow = train_X + (size_t)(j0 + jj) * DIM;
        float d0 = 0.f, d1 = 0.f, d2 = 0.f, d3 = 0.f;
        #pragma unroll
        for (int k4 = 0; k4 < DIM / 4; ++k4) {
            float4 t = reinterpret_cast<const float4*>(trow)[k4];
            d0 = fmaf(xr[4*k4+0], t.x, d0);
            d1 = fmaf(xr[4*k4+1], t.y, d1);
            d2 = fmaf(xr[4*k4+2], t.z, d2);
            d3 = fmaf(xr[4*k4+3], t.w, d3);
        }
        float dot = (d0 + d1) + (d2 + d3);
        float sq  = nxv + nt_lds[jj] - 2.0f * dot;
        sq = fmaxf(sq, 0.0f);
        acc = fmaf(__expf(-0.5f * sq), al_lds[jj], acc);
    }
    atomicAdd(&out[i], acc);
}

extern "C" void kernel_launch(void* const* d_in, const int* in_sizes, int n_in,
                              void* d_out, int out_size, void* d_ws, size_t ws_size,
                              hipStream_t stream) {
    const float* test_X      = (const float*)d_in[0];
    const float* train_X     = (const float*)d_in[1];
    const float* alphas      = (const float*)d_in[2];
    const float* lengthscale = (const float*)d_in[3];
    float* out = (float*)d_out;

    const size_t need = (size_t)(NTEST + NTRAIN) * DIM * sizeof(_Float16)
                      + (NTEST + NTRAIN) * sizeof(float);
    if (ws_size >= need) {
        _Float16* A_hi = (_Float16*)d_ws;
        _Float16* B_hi = A_hi + (size_t)NTEST * DIM;
        float*    nx2  = (float*)(B_hi + (size_t)NTRAIN * DIM);
        float*    wtp  = nx2 + NTEST;

        // prep also zeroes `out` (memset launch folded in).
        krr_prep<<<(NTEST + NTRAIN) / 4, 256, 0, stream>>>(
            test_X, train_X, alphas, lengthscale, A_hi, B_hi, nx2, wtp, out);

        dim3 grid(NTEST / 256, NCOLSPLIT);
        krr_mfma<<<grid, 64 * WPB, 0, stream>>>(A_hi, B_hi, nx2, wtp,
                                                lengthscale, out);
    } else {
        hipMemsetAsync(out, 0, NTEST * sizeof(float), stream);
        dim3 grid(NTEST / 256, NCHUNK);
        krr_main<<<grid, 256, 0, stream>>>(test_X, train_X, alphas, lengthscale, out);
    }
}

// Round 19
// 38.836 us; speedup vs baseline: 2.5431x; 1.0871x over previous
//
#include <hip/hip_runtime.h>

#define NTEST  16384
#define NTRAIN 8192
#define DIM    64
#define NCOLSPLIT 16
#define WPB    8                            // waves per block (512 threads)

typedef _Float16 f16x8  __attribute__((ext_vector_type(8)));
typedef float    f32x16 __attribute__((ext_vector_type(16)));

#define LOG2E 1.4426950408889634f

// Direct global->LDS DMA: no staging VGPRs, linear wave-contiguous LDS writes.
#define GLOAD_LDS16(gsrc, ldst)                                                     \
    __builtin_amdgcn_global_load_lds(                                               \
        (const __attribute__((address_space(1))) unsigned int*)(gsrc),              \
        (__attribute__((address_space(3))) unsigned int*)(ldst), 16, 0, 0)

// Rows [0,NTEST) = test_X -> A_hi = f16(x * s1) (PRE-SCALED by inv2*log2e so
// the MFMA emits the exp argument's dot term directly) + nx2 = cn*nx
// (+ zeroes out[row]). Rows [NTEST,..) = train_X -> B_hi = f16(x) UNSCALED
// (only one operand side may carry the scale) in TILE-MAJOR layout +
// wt = alpha * exp2(cn*nt).
// Tile-major: for train row r, dim k:
//   flat = (r>>5)*2048 + (k>>4)*512 + (((k>>3)&1)*32 + (r&31))*8 + (k&7)
__global__ __launch_bounds__(256) void krr_prep(
    const float* __restrict__ test_X, const float* __restrict__ train_X,
    const float* __restrict__ alphas, const float* __restrict__ lengthscale,
    _Float16* __restrict__ A_hi, _Float16* __restrict__ B_hi,
    float* __restrict__ nx2, float* __restrict__ wt, float* __restrict__ out)
{
    int gwave = (blockIdx.x * 256 + threadIdx.x) >> 6;
    int lane  = threadIdx.x & 63;           // = dim index k
    bool is_test = gwave < NTEST;
    int row = is_test ? gwave : gwave - NTEST;
    const float* src = is_test ? test_X : train_X;

    float ls   = lengthscale[0];
    float inv2 = 1.0f / (ls * ls);
    float s1   = inv2 * LOG2E;               // dot coefficient (log2 domain)
    float cn   = -0.5f * inv2 * LOG2E;       // norm coefficient (log2 domain)

    float x = src[(size_t)row * DIM + lane];

    if (is_test) {
        A_hi[(size_t)row * DIM + lane] = (_Float16)(x * s1);  // pre-scaled
    } else {
        _Float16 h = (_Float16)x;                             // unscaled
        int t  = row >> 5, lr = row & 31;
        int kk = lane >> 4, hi = (lane >> 3) & 1, e = lane & 7;
        size_t dst = (size_t)t * 2048 + (size_t)kk * 512 + (size_t)(hi * 32 + lr) * 8 + e;
        B_hi[dst] = h;
    }

    float s = x * x;
    s += __shfl_xor(s, 1);  s += __shfl_xor(s, 2);  s += __shfl_xor(s, 4);
    s += __shfl_xor(s, 8);  s += __shfl_xor(s, 16); s += __shfl_xor(s, 32);
    if (lane == 0) {
        if (is_test) { nx2[row] = s * cn; out[row] = 0.0f; }
        else         wt[row]  = alphas[row] * __builtin_amdgcn_exp2f(cn * s);
    }
}

// r18 structure + EPILOGUE FOLDED INTO MFMA (round-18 diagnosis: issue-bound,
// ~350 issue-cyc/wave/pair-iter vs 256 MFMA-pipe-cyc at the VGPR-capped
// 4 waves/SIMD). Changes: (1) A pre-scaled by s1 -> MFMA result IS the
// scaled dot; (2) each chain's FIRST MFMA takes nxcv (cn*nx row constants)
// as its C-input (D != C is legal) -> zero-init movs AND the nxc-add vanish
// into the matrix pipe. Epilogue per element: exp2 + fma — the floor.
// Rotation, staging, layout identical to r18 (proven clean).
// K*alpha = exp2(C[r]) * wt[col], with C = cn*nx + s1*dot after the chain.
__global__ __launch_bounds__(512) void krr_mfma(
    const _Float16* __restrict__ A_hi, const _Float16* __restrict__ B_hi,
    const float* __restrict__ nx2, const float* __restrict__ wt,
    const float* __restrict__ lengthscale, float* __restrict__ out)
{
    alignas(16) __shared__ _Float16 BsA[8 * 2048];  // 32 KB (phase 0)
    alignas(16) __shared__ _Float16 BsB[8 * 2048];  // 32 KB (phase 1)
    __shared__ float wts[512];                      // 2 KB

    const int tid   = threadIdx.x;
    const int lane  = tid & 63;
    const int wave  = tid >> 6;
    const int rbase = blockIdx.x * 256 + wave * 32;
    const int cb    = blockIdx.y;                   // col-split index

    // Wave w DMAs tile (p*8 + w) of the strip: 4 x 1KB global_load_lds.
    #define STAGE8(p, buf)                                                      \
        {                                                                       \
            const _Float16* gt = B_hi + ((size_t)cb * 16 + (p) * 8 + wave) * 2048 \
                               + (size_t)lane * 8;                              \
            _Float16* lt0 = (buf) + (size_t)wave * 2048;                        \
            GLOAD_LDS16(gt,        lt0);                                        \
            GLOAD_LDS16(gt + 512,  lt0 + 512);                                  \
            GLOAD_LDS16(gt + 1024, lt0 + 1024);                                 \
            GLOAD_LDS16(gt + 1536, lt0 + 1536);                                 \
        }

    // Compute 8 tiles of phase p: pair-rotated (r18). Chains seeded with
    // nxcv via the first MFMA's C operand; epilogue = exp2 + fma only.
    #define COMPUTE8(p, buf)                                                    \
        {                                                                       \
            const _Float16* pbase = (buf) + (size_t)lane * 8;                   \
            f16x8 bhA[4], bhB[4];                                               \
            _Pragma("unroll")                                                   \
            for (int kk = 0; kk < 4; ++kk) {                                    \
                bhA[kk] = *reinterpret_cast<const f16x8*>(pbase + kk * 512);    \
                bhB[kk] = *reinterpret_cast<const f16x8*>(pbase + 2048 + kk * 512); \
            }                                                                   \
            _Pragma("unroll 1")                                                 \
            for (int lt = 0; lt < 8; lt += 2) {                                 \
                f32x16 CA = __builtin_amdgcn_mfma_f32_32x32x16_f16(ah[0], bhA[0], nxcv, 0, 0, 0); \
                f32x16 CB = __builtin_amdgcn_mfma_f32_32x32x16_f16(ah[0], bhB[0], nxcv, 0, 0, 0); \
                _Pragma("unroll")                                               \
                for (int kk = 1; kk < 4; ++kk) {                                \
                    CA = __builtin_amdgcn_mfma_f32_32x32x16_f16(ah[kk], bhA[kk], CA, 0, 0, 0); \
                    CB = __builtin_amdgcn_mfma_f32_32x32x16_f16(ah[kk], bhB[kk], CB, 0, 0, 0); \
                }                                                               \
                const int wtb = ((p) * 8 + lt) * 32 + (lane & 31);              \
                const float wA = wts[wtb];                                      \
                const float wB = wts[wtb + 32];                                 \
                if (lt < 6) {                                                   \
                    const _Float16* pn = pbase + (size_t)(lt + 2) * 2048;       \
                    _Pragma("unroll")                                           \
                    for (int kk = 0; kk < 4; ++kk) {                            \
                        bhA[kk] = *reinterpret_cast<const f16x8*>(pn + kk * 512); \
                        bhB[kk] = *reinterpret_cast<const f16x8*>(pn + 2048 + kk * 512); \
                    }                                                           \
                }                                                               \
                _Pragma("unroll")                                               \
                for (int r = 0; r < 16; ++r) {                                  \
                    acc[r] = fmaf(__builtin_amdgcn_exp2f(CA[r]), wA, acc[r]);   \
                    acc[r] = fmaf(__builtin_amdgcn_exp2f(CB[r]), wB, acc[r]);   \
                }                                                               \
            }                                                                   \
        }

    // Issue phase-0 stage + weights immediately.
    STAGE8(0, BsA);
    wts[tid] = wt[cb * 512 + tid];

    const int arow = rbase + (lane & 31);
    const int koff = (lane >> 5) * 8;        // canonical k-map, same for A and B

    // A fragments (pre-scaled by s1), loop-invariant: 4 x 16B = 16 VGPRs
    f16x8 ah[4];
    #pragma unroll
    for (int kk = 0; kk < 4; ++kk)
        ah[kk] = *reinterpret_cast<const f16x8*>(A_hi + (size_t)arow * DIM + kk * 16 + koff);

    // C-seed: cn*nx for the 16 C/D rows this lane holds (consumed by the
    // first MFMA of every chain as its C operand).
    f32x16 nxcv;
    #pragma unroll
    for (int r = 0; r < 16; ++r) {
        int row = (r & 3) + 8 * (r >> 2) + 4 * (lane >> 5);
        nxcv[r] = nx2[rbase + row];
    }

    float acc[16];
    #pragma unroll
    for (int r = 0; r < 16; ++r) acc[r] = 0.0f;

    __syncthreads();              // BsA ready (the one exposed stage wait)

    STAGE8(1, BsB);               // issued now; latency hidden under COMPUTE8(0)
    COMPUTE8(0, BsA);

    __syncthreads();              // drains BsB loads (covered by compute above)

    COMPUTE8(1, BsB);

    #undef STAGE8
    #undef COMPUTE8

    // Sum over the 32 train cols held across lanes of the same half.
    #pragma unroll
    for (int r = 0; r < 16; ++r) {
        float v = acc[r];
        v += __shfl_xor(v, 1);  v += __shfl_xor(v, 2);  v += __shfl_xor(v, 4);
        v += __shfl_xor(v, 8);  v += __shfl_xor(v, 16);
        if ((lane & 31) == 0) {
            int row = (r & 3) + 8 * (r >> 2) + 4 * (lane >> 5);
            atomicAdd(&out[rbase + row], v);
        }
    }
}

// ---------------- fallback (round-1 kernel, known-good) ----------------
#define TCHUNK 512
#define NCHUNK (NTRAIN / TCHUNK)
__global__ __launch_bounds__(256, 4) void krr_main(
    const float* __restrict__ test_X, const float* __restrict__ train_X,
    const float* __restrict__ alphas, const float* __restrict__ lengthscale,
    float* __restrict__ out)
{
    __shared__ float nt_lds[TCHUNK];
    __shared__ float al_lds[TCHUNK];
    const int tid = threadIdx.x;
    const int i   = blockIdx.x * 256 + tid;
    const int j0  = blockIdx.y * TCHUNK;
    const float ls   = lengthscale[0];
    const float inv2 = 1.0f / (ls * ls);
    for (int jj = tid; jj < TCHUNK; jj += 256) {
        const float4* tr = reinterpret_cast<const float4*>(train_X + (size_t)(j0 + jj) * DIM);
        float s = 0.f;
        #pragma unroll
        for (int k = 0; k < DIM / 4; ++k) {
            float4 t = tr[k];
            s += t.x * t.x + t.y * t.y + t.z * t.z + t.w * t.w;
        }
        nt_lds[jj] = s * inv2;
        al_lds[jj] = alphas[j0 + jj];
    }
    __syncthreads();
    float xr[DIM]; float nxv = 0.f;
    {
        const float4* xp = reinterpret_cast<const float4*>(test_X + (size_t)i * DIM);
        #pragma unroll
        for (int k = 0; k < DIM / 4; ++k) {
            float4 v = xp[k];
            xr[4*k+0] = v.x; xr[4*k+1] = v.y; xr[4*k+2] = v.z; xr[4*k+3] = v.w;
            nxv += v.x*v.x + v.y*v.y + v.z*v.z + v.w*v.w;
        }
        nxv *= inv2;
        #pragma unroll
        for (int k = 0; k < DIM; ++k) xr[k] *= inv2;
    }
    float acc = 0.f;
    for (int jj = 0; jj < TCHUNK; ++jj) {
        const float* trow = train_X + (size_t)(j0 + jj) * DIM;
        float d0 = 0.f, d1 = 0.f, d2 = 0.f, d3 = 0.f;
        #pragma unroll
        for (int k4 = 0; k4 < DIM / 4; ++k4) {
            float4 t = reinterpret_cast<const float4*>(trow)[k4];
            d0 = fmaf(xr[4*k4+0], t.x, d0);
            d1 = fmaf(xr[4*k4+1], t.y, d1);
            d2 = fmaf(xr[4*k4+2], t.z, d2);
            d3 = fmaf(xr[4*k4+3], t.w, d3);
        }
        float dot = (d0 + d1) + (d2 + d3);
        float sq  = nxv + nt_lds[jj] - 2.0f * dot;
        sq = fmaxf(sq, 0.0f);
        acc = fmaf(__expf(-0.5f * sq), al_lds[jj], acc);
    }
    atomicAdd(&out[i], acc);
}

extern "C" void kernel_launch(void* const* d_in, const int* in_sizes, int n_in,
                              void* d_out, int out_size, void* d_ws, size_t ws_size,
                              hipStream_t stream) {
    const float* test_X      = (const float*)d_in[0];
    const float* train_X     = (const float*)d_in[1];
    const float* alphas      = (const float*)d_in[2];
    const float* lengthscale = (const float*)d_in[3];
    float* out = (float*)d_out;

    const size_t need = (size_t)(NTEST + NTRAIN) * DIM * sizeof(_Float16)
                      + (NTEST + NTRAIN) * sizeof(float);
    if (ws_size >= need) {
        _Float16* A_hi = (_Float16*)d_ws;
        _Float16* B_hi = A_hi + (size_t)NTEST * DIM;
        float*    nx2  = (float*)(B_hi + (size_t)NTRAIN * DIM);
        float*    wtp  = nx2 + NTEST;

        // prep also zeroes `out` (memset launch folded in).
        krr_prep<<<(NTEST + NTRAIN) / 4, 256, 0, stream>>>(
            test_X, train_X, alphas, lengthscale, A_hi, B_hi, nx2, wtp, out);

        dim3 grid(NTEST / 256, NCOLSPLIT);
        krr_mfma<<<grid, 64 * WPB, 0, stream>>>(A_hi, B_hi, nx2, wtp,
                                                lengthscale, out);
    } else {
        hipMemsetAsync(out, 0, NTEST * sizeof(float), stream);
        dim3 grid(NTEST / 256, NCHUNK);
        krr_main<<<grid, 256, 0, stream>>>(test_X, train_X, alphas, lengthscale, out);
    }
}